// Round 2
// baseline (3184.918 us; speedup 1.0000x reference)
//
#include <hip/hip_runtime.h>
#include <hip/hip_fp16.h>
#include <math.h>
#include <type_traits>

// Problem dims (fixed): B=16, S=2048, D=512, H=512
#define SQ   2048
#define HID  512
#define N3   1536   // 3H (Z|F|O)
#define N2   1024   // 2H
#define NB   16

typedef __attribute__((ext_vector_type(8))) _Float16 half8;
typedef __attribute__((ext_vector_type(4))) _Float16 half4v;
typedef __attribute__((ext_vector_type(4))) float    floatx4;

// ZFO = act(A[M,K] @ W[K,1536] + bias), fp32 out. A is fp32 (layer1: X) or
// fp16 (layer2: Y1). W/bias fp32, converted to fp16 during LDS staging.
// act: cols [0,512)=tanh(Z), [512,1536)=sigmoid(F,O).
// Tile 128x128, BK=32, 4 waves (2x2), 4x4 mfma_f32_16x16x32_f16 per wave.
template <typename AT>
__global__ __launch_bounds__(256) void qrnn_gemm_bias_act(
    const AT* __restrict__ A,
    const float* __restrict__ W,
    const float* __restrict__ bias,
    float* __restrict__ ZFO,
    int K)
{
    // pad rows to 40 halfs (80 B): row start bank = (20*row)%32 -> worst 2-way (free)
    __shared__ _Float16 lds_a[128][40];   // [m][k]
    __shared__ _Float16 lds_b[128][40];   // [n][k] (transposed in staging)

    const int tid  = threadIdx.x;
    const int lane = tid & 63;
    const int w    = tid >> 6;
    const int wm   = w >> 1;
    const int wn   = w & 1;
    const int m0   = blockIdx.x * 128;
    const int n0   = blockIdx.y * 128;
    const int m16  = lane & 15;
    const int kb   = lane >> 4;       // 0..3 (k-block of 8)

    floatx4 acc[4][4] = {};

    for (int k0 = 0; k0 < K; k0 += 32) {
        // ---- stage A tile (128 x 32) ----
        if constexpr (std::is_same<AT, float>::value) {
            #pragma unroll
            for (int i = 0; i < 4; ++i) {
                int chunk = tid + i * 256;            // 0..1023
                int row   = chunk >> 3;               // 0..127
                int col   = (chunk & 7) * 4;          // 0..28
                floatx4 v = *(const floatx4*)(A + (size_t)(m0 + row) * K + k0 + col);
                half4v h = { (_Float16)v[0], (_Float16)v[1], (_Float16)v[2], (_Float16)v[3] };
                *(half4v*)&lds_a[row][col] = h;       // 8 B, aligned (col*2 % 8 == 0)
            }
        } else {
            #pragma unroll
            for (int i = 0; i < 2; ++i) {
                int chunk = tid + i * 256;            // 0..511
                int row   = chunk >> 2;               // 0..127
                int col   = (chunk & 3) * 8;          // 0,8,16,24
                *(half8*)&lds_a[row][col] =
                    *(const half8*)(A + (size_t)(m0 + row) * K + k0 + col);
            }
        }
        // ---- stage W tile transposed (32 k x 128 n) with fp32->fp16 ----
        #pragma unroll
        for (int i = 0; i < 4; ++i) {
            int chunk = tid + i * 256;                // 0..1023
            int k  = chunk >> 5;                      // 0..31
            int nc = (chunk & 31) * 4;                // 0..124
            floatx4 v = *(const floatx4*)(W + (size_t)(k0 + k) * N3 + n0 + nc);
            #pragma unroll
            for (int e = 0; e < 4; ++e) lds_b[nc + e][k] = (_Float16)v[e];
        }
        __syncthreads();

        half8 af[4], bf[4];
        #pragma unroll
        for (int i = 0; i < 4; ++i)
            af[i] = *(const half8*)&lds_a[wm * 64 + i * 16 + m16][kb * 8];
        #pragma unroll
        for (int j = 0; j < 4; ++j)
            bf[j] = *(const half8*)&lds_b[wn * 64 + j * 16 + m16][kb * 8];
        #pragma unroll
        for (int i = 0; i < 4; ++i)
            #pragma unroll
            for (int j = 0; j < 4; ++j)
                acc[i][j] = __builtin_amdgcn_mfma_f32_16x16x32_f16(
                                af[i], bf[j], acc[i][j], 0, 0, 0);
        __syncthreads();
    }

    // epilogue: D row=(lane>>4)*4+r, col=lane&15 (m89/m91 mapping, dtype-independent)
    const int rbase = (lane >> 4) * 4;
    const int cbase = lane & 15;
    #pragma unroll
    for (int i = 0; i < 4; ++i) {
        #pragma unroll
        for (int j = 0; j < 4; ++j) {
            int n = n0 + wn * 64 + j * 16 + cbase;
            float bv = bias[n];
            #pragma unroll
            for (int r = 0; r < 4; ++r) {
                int m = m0 + wm * 64 + i * 16 + rbase + r;
                float v = acc[i][j][r] + bv;
                if (n < HID) v = tanhf(v);
                else         v = 1.0f / (1.0f + __expf(-v));
                ZFO[(size_t)m * N3 + n] = v;
            }
        }
    }
}

// fo-pooling scan: one thread per (b,h) chain. c = f*c + (1-f)*z; y = o*c.
// reverse=1 runs s from S-1 down. OT = _Float16 (Y1) or float (final out).
template <typename OT>
__global__ __launch_bounds__(256) void qrnn_scan(
    const float* __restrict__ ZFO,
    OT* __restrict__ out,            // chunk base, row stride N2
    int reverse, int col_ofs)
{
    int t = blockIdx.x * blockDim.x + threadIdx.x;
    int b = t >> 9;                  // chunk-local batch
    int h = t & 511;
    size_t base = (size_t)b * SQ * N3 + h;
    size_t ob   = (size_t)b * SQ * N2 + col_ofs + h;
    float c = 0.0f;
    if (!reverse) {
        size_t r = base, o = ob;
        #pragma unroll 4
        for (int s = 0; s < SQ; ++s) {
            float z = ZFO[r], f = ZFO[r + HID], og = ZFO[r + 2 * HID];
            c = f * c + (1.0f - f) * z;
            out[o] = (OT)(og * c);
            r += N3; o += N2;
        }
    } else {
        size_t r = base + (size_t)(SQ - 1) * N3;
        size_t o = ob + (size_t)(SQ - 1) * N2;
        #pragma unroll 4
        for (int s = 0; s < SQ; ++s) {
            float z = ZFO[r], f = ZFO[r + HID], og = ZFO[r + 2 * HID];
            c = f * c + (1.0f - f) * z;
            out[o] = (OT)(og * c);
            r -= N3; o -= N2;
        }
    }
}

extern "C" void kernel_launch(void* const* d_in, const int* in_sizes, int n_in,
                              void* d_out, int out_size, void* d_ws, size_t ws_size,
                              hipStream_t stream)
{
    // inputs (fp32 per reference): X, seqlens(i32,unused),
    // W_fw0, b_fw0, W_bw0, b_bw0, W_fw1, b_fw1, W_bw1, b_bw1
    const float* X = (const float*)d_in[0];
    const float* Wd[2][2] = {
        { (const float*)d_in[2], (const float*)d_in[4] },
        { (const float*)d_in[6], (const float*)d_in[8] } };
    const float* bd[2][2] = {
        { (const float*)d_in[3], (const float*)d_in[5] },
        { (const float*)d_in[7], (const float*)d_in[9] } };
    float* OUT = (float*)d_out;

    // ws layout: Y1 fp16 [NB*SQ, N2] (32 MiB) | ZFO fp32 chunk (12 MiB/batch)
    _Float16* Y1 = (_Float16*)d_ws;
    size_t y1_bytes = (size_t)NB * SQ * N2 * sizeof(_Float16);
    float* ZFO = (float*)((char*)d_ws + y1_bytes);
    size_t per_b = (size_t)SQ * N3 * sizeof(float);
    size_t avail = (ws_size > y1_bytes) ? (ws_size - y1_bytes) : per_b;
    int cbmax = (int)(avail / per_b);
    if (cbmax > NB) cbmax = NB;
    if (cbmax < 1)  cbmax = 1;

    for (int layer = 0; layer < 2; ++layer) {
        int K = (layer == 0) ? 512 : 1024;
        for (int dir = 0; dir < 2; ++dir) {
            for (int c0 = 0; c0 < NB; c0 += cbmax) {
                int cb = (cbmax < NB - c0) ? cbmax : (NB - c0);
                int M = cb * SQ;                       // multiple of 128
                dim3 grid(M / 128, N3 / 128);
                if (layer == 0) {
                    qrnn_gemm_bias_act<float><<<grid, 256, 0, stream>>>(
                        X + (size_t)c0 * SQ * K, Wd[layer][dir], bd[layer][dir], ZFO, K);
                    int nt = cb * HID;
                    qrnn_scan<_Float16><<<nt / 256, 256, 0, stream>>>(
                        ZFO, Y1 + (size_t)c0 * SQ * N2, dir, dir == 0 ? 0 : HID);
                } else {
                    qrnn_gemm_bias_act<_Float16><<<grid, 256, 0, stream>>>(
                        Y1 + (size_t)c0 * SQ * K, Wd[layer][dir], bd[layer][dir], ZFO, K);
                    int nt = cb * HID;
                    qrnn_scan<float><<<nt / 256, 256, 0, stream>>>(
                        ZFO, OUT + (size_t)c0 * SQ * N2, dir, dir == 0 ? 0 : HID);
                }
            }
        }
    }
}

// Round 3
// 1811.044 us; speedup vs baseline: 1.7586x; 1.7586x over previous
//
#include <hip/hip_runtime.h>
#include <hip/hip_fp16.h>
#include <math.h>
#include <type_traits>

// Problem dims (fixed): B=16, S=2048, D=512, H=512
#define SQ   2048
#define HID  512
#define N3   1536   // 3H (Z|F|O)
#define N2   1024   // 2H
#define NB   16
#define NC   64     // scan chunks per chain
#define NCLOG 6
#define LCH  32     // chunk length = SQ/NC

typedef __attribute__((ext_vector_type(8))) _Float16 half8;
typedef __attribute__((ext_vector_type(4))) _Float16 half4v;
typedef __attribute__((ext_vector_type(2))) _Float16 half2v;
typedef __attribute__((ext_vector_type(4))) float    floatx4;
typedef __attribute__((ext_vector_type(2))) float    floatx2;

// ============================ GEMM + bias + act ============================
// ZFO = act(A[M,K] @ W[K,1536] + bias), fp32 out. A fp32 (layer1) or fp16 (layer2).
// W/bias fp32, converted to fp16 during LDS staging.
// Tile 128x128, BK=32, 4 waves (2x2), 4x4 mfma_f32_16x16x32_f16 per wave.
template <typename AT>
__global__ __launch_bounds__(256) void qrnn_gemm_bias_act(
    const AT* __restrict__ A,
    const float* __restrict__ W,
    const float* __restrict__ bias,
    float* __restrict__ ZFO,
    int K)
{
    __shared__ _Float16 lds_a[128][40];   // [m][k], pad->worst 2-way conflict (free)
    __shared__ _Float16 lds_b[128][40];   // [n][k]

    const int tid  = threadIdx.x;
    const int lane = tid & 63;
    const int w    = tid >> 6;
    const int wm   = w >> 1;
    const int wn   = w & 1;
    const int m0   = blockIdx.x * 128;
    const int n0   = blockIdx.y * 128;
    const int m16  = lane & 15;
    const int kb   = lane >> 4;

    floatx4 acc[4][4] = {};

    for (int k0 = 0; k0 < K; k0 += 32) {
        if constexpr (std::is_same<AT, float>::value) {
            #pragma unroll
            for (int i = 0; i < 4; ++i) {
                int chunk = tid + i * 256;
                int row   = chunk >> 3;
                int col   = (chunk & 7) * 4;
                floatx4 v = *(const floatx4*)(A + (size_t)(m0 + row) * K + k0 + col);
                half4v h = { (_Float16)v[0], (_Float16)v[1], (_Float16)v[2], (_Float16)v[3] };
                *(half4v*)&lds_a[row][col] = h;
            }
        } else {
            #pragma unroll
            for (int i = 0; i < 2; ++i) {
                int chunk = tid + i * 256;
                int row   = chunk >> 2;
                int col   = (chunk & 3) * 8;
                *(half8*)&lds_a[row][col] =
                    *(const half8*)(A + (size_t)(m0 + row) * K + k0 + col);
            }
        }
        #pragma unroll
        for (int i = 0; i < 4; ++i) {
            int chunk = tid + i * 256;
            int k  = chunk >> 5;
            int nc = (chunk & 31) * 4;
            floatx4 v = *(const floatx4*)(W + (size_t)(k0 + k) * N3 + n0 + nc);
            #pragma unroll
            for (int e = 0; e < 4; ++e) lds_b[nc + e][k] = (_Float16)v[e];
        }
        __syncthreads();

        half8 af[4], bf[4];
        #pragma unroll
        for (int i = 0; i < 4; ++i)
            af[i] = *(const half8*)&lds_a[wm * 64 + i * 16 + m16][kb * 8];
        #pragma unroll
        for (int j = 0; j < 4; ++j)
            bf[j] = *(const half8*)&lds_b[wn * 64 + j * 16 + m16][kb * 8];
        #pragma unroll
        for (int i = 0; i < 4; ++i)
            #pragma unroll
            for (int j = 0; j < 4; ++j)
                acc[i][j] = __builtin_amdgcn_mfma_f32_16x16x32_f16(
                                af[i], bf[j], acc[i][j], 0, 0, 0);
        __syncthreads();
    }

    const int rbase = (lane >> 4) * 4;
    const int cbase = lane & 15;
    #pragma unroll
    for (int i = 0; i < 4; ++i) {
        #pragma unroll
        for (int j = 0; j < 4; ++j) {
            int n = n0 + wn * 64 + j * 16 + cbase;
            float bv = bias[n];
            #pragma unroll
            for (int r = 0; r < 4; ++r) {
                int m = m0 + wm * 64 + i * 16 + rbase + r;
                float v = acc[i][j][r] + bv;
                if (n < HID) v = tanhf(v);
                else         v = 1.0f / (1.0f + __expf(-v));
                ZFO[(size_t)m * N3 + n] = v;
            }
        }
    }
}

// ============================ chunked parallel scan ============================
// c_s = f*c + (1-f)*z over S, split into NC chunks of LCH. Each chunk reduces to
// c_out = F * c_in + C. Phase 1 computes (F,C); phase 2 scans chunk summaries;
// phase 3 replays with known c_in and applies output gate.
// Thread handles 2 adjacent h (float2). Summary layout: [b][chunk][hh=h/2].

__global__ __launch_bounds__(256) void qrnn_scan_sum(
    const float* __restrict__ ZFO,
    floatx2* __restrict__ Fs, floatx2* __restrict__ Cs,
    int reverse)
{
    int t  = blockIdx.x * 256 + threadIdx.x;
    int hh = t & 255;
    int bj = t >> 8;              // b*NC + j
    int j  = bj & (NC - 1);
    int b  = bj >> NCLOG;
    int h2 = hh * 2;
    const float* base = ZFO + (size_t)b * SQ * N3 + h2;
    float F0 = 1.f, F1 = 1.f, c0 = 0.f, c1 = 0.f;
    int s0 = j * LCH;
    #pragma unroll 4
    for (int i = 0; i < LCH; ++i) {
        int s = reverse ? (s0 + LCH - 1 - i) : (s0 + i);
        const float* p = base + (size_t)s * N3;
        floatx2 z = *(const floatx2*)p;
        floatx2 f = *(const floatx2*)(p + HID);
        F0 *= f[0]; F1 *= f[1];
        c0 = f[0] * c0 + (1.f - f[0]) * z[0];
        c1 = f[1] * c1 + (1.f - f[1]) * z[1];
    }
    Fs[(size_t)bj * 256 + hh] = floatx2{F0, F1};
    Cs[(size_t)bj * 256 + hh] = floatx2{c0, c1};
}

__global__ __launch_bounds__(256) void qrnn_scan_mid(
    const floatx2* __restrict__ Fs, const floatx2* __restrict__ Cs,
    floatx2* __restrict__ cin, int reverse)
{
    int t  = blockIdx.x * 256 + threadIdx.x;
    int hh = t & 255;
    int b  = t >> 8;
    float c0 = 0.f, c1 = 0.f;
    for (int i = 0; i < NC; ++i) {
        int j = reverse ? (NC - 1 - i) : i;
        size_t idx = ((size_t)b * NC + j) * 256 + hh;
        cin[idx] = floatx2{c0, c1};
        floatx2 F = Fs[idx], C = Cs[idx];
        c0 = F[0] * c0 + C[0];
        c1 = F[1] * c1 + C[1];
    }
}

template <typename OT>
__global__ __launch_bounds__(256) void qrnn_scan_out(
    const float* __restrict__ ZFO,
    const floatx2* __restrict__ cin,
    OT* __restrict__ out,            // chunk-batch base, row stride N2
    int reverse, int col_ofs)
{
    int t  = blockIdx.x * 256 + threadIdx.x;
    int hh = t & 255;
    int bj = t >> 8;
    int j  = bj & (NC - 1);
    int b  = bj >> NCLOG;
    int h2 = hh * 2;
    const float* base = ZFO + (size_t)b * SQ * N3 + h2;
    floatx2 c = cin[(size_t)bj * 256 + hh];
    float c0 = c[0], c1 = c[1];
    int s0 = j * LCH;
    #pragma unroll 4
    for (int i = 0; i < LCH; ++i) {
        int s = reverse ? (s0 + LCH - 1 - i) : (s0 + i);
        const float* p = base + (size_t)s * N3;
        floatx2 z = *(const floatx2*)p;
        floatx2 f = *(const floatx2*)(p + HID);
        floatx2 o = *(const floatx2*)(p + 2 * HID);
        c0 = f[0] * c0 + (1.f - f[0]) * z[0];
        c1 = f[1] * c1 + (1.f - f[1]) * z[1];
        OT* q = out + (size_t)(b * SQ + s) * N2 + col_ofs + h2;
        if constexpr (std::is_same<OT, float>::value) {
            *(floatx2*)q = floatx2{o[0] * c0, o[1] * c1};
        } else {
            *(half2v*)q = half2v{(_Float16)(o[0] * c0), (_Float16)(o[1] * c1)};
        }
    }
}

// ============================ launcher ============================
extern "C" void kernel_launch(void* const* d_in, const int* in_sizes, int n_in,
                              void* d_out, int out_size, void* d_ws, size_t ws_size,
                              hipStream_t stream)
{
    const float* X = (const float*)d_in[0];
    const float* Wd[2][2] = {
        { (const float*)d_in[2], (const float*)d_in[4] },
        { (const float*)d_in[6], (const float*)d_in[8] } };
    const float* bd[2][2] = {
        { (const float*)d_in[3], (const float*)d_in[5] },
        { (const float*)d_in[7], (const float*)d_in[9] } };
    float* OUT = (float*)d_out;

    // ws: Y1 fp16 (32 MiB) | Fs | Cs | cin (2 MiB each) | ZFO fp32 chunk (12 MiB/batch)
    char* p = (char*)d_ws;
    _Float16* Y1 = (_Float16*)p;            p += (size_t)NB * SQ * N2 * sizeof(_Float16);
    size_t sum_elems = (size_t)NB * NC * 256;
    floatx2* Fs  = (floatx2*)p;             p += sum_elems * sizeof(floatx2);
    floatx2* Cs  = (floatx2*)p;             p += sum_elems * sizeof(floatx2);
    floatx2* cin = (floatx2*)p;             p += sum_elems * sizeof(floatx2);
    float* ZFO = (float*)p;
    size_t used = (size_t)(p - (char*)d_ws);
    size_t per_b = (size_t)SQ * N3 * sizeof(float);
    size_t avail = (ws_size > used) ? (ws_size - used) : per_b;
    int cbmax = (int)(avail / per_b);
    if (cbmax > NB) cbmax = NB;
    if (cbmax < 1)  cbmax = 1;

    for (int layer = 0; layer < 2; ++layer) {
        int K = (layer == 0) ? 512 : 1024;
        for (int dir = 0; dir < 2; ++dir) {
            for (int c0 = 0; c0 < NB; c0 += cbmax) {
                int cb = (cbmax < NB - c0) ? cbmax : (NB - c0);
                int M = cb * SQ;
                dim3 grid(M / 128, N3 / 128);
                int colofs = (dir == 0) ? 0 : HID;
                if (layer == 0) {
                    qrnn_gemm_bias_act<float><<<grid, 256, 0, stream>>>(
                        X + (size_t)c0 * SQ * K, Wd[layer][dir], bd[layer][dir], ZFO, K);
                } else {
                    qrnn_gemm_bias_act<_Float16><<<grid, 256, 0, stream>>>(
                        Y1 + (size_t)c0 * SQ * K, Wd[layer][dir], bd[layer][dir], ZFO, K);
                }
                qrnn_scan_sum<<<cb * NC, 256, 0, stream>>>(ZFO, Fs, Cs, dir);
                qrnn_scan_mid<<<cb, 256, 0, stream>>>(Fs, Cs, cin, dir);
                if (layer == 0) {
                    qrnn_scan_out<_Float16><<<cb * NC, 256, 0, stream>>>(
                        ZFO, cin, Y1 + (size_t)c0 * SQ * N2, dir, colofs);
                } else {
                    qrnn_scan_out<float><<<cb * NC, 256, 0, stream>>>(
                        ZFO, cin, OUT + (size_t)c0 * SQ * N2, dir, colofs);
                }
            }
        }
    }
}

// Round 4
// 986.641 us; speedup vs baseline: 3.2280x; 1.8356x over previous
//
#include <hip/hip_runtime.h>
#include <hip/hip_fp16.h>
#include <math.h>
#include <stdint.h>
#include <type_traits>

// Problem dims (fixed): B=16, S=2048, D=512, H=512
#define SQ   2048
#define HID  512
#define N3   1536   // 3H (Z|F|O)
#define N2   1024   // 2H
#define NB   16
#define NC   64     // scan chunks per chain
#define NCLOG 6
#define LCH  32     // chunk length = SQ/NC

typedef __attribute__((ext_vector_type(8))) _Float16 half8;
typedef __attribute__((ext_vector_type(4))) _Float16 half4v;
typedef __attribute__((ext_vector_type(2))) _Float16 half2v;
typedef __attribute__((ext_vector_type(4))) float    floatx4;
typedef __attribute__((ext_vector_type(2))) float    floatx2;

// async global->LDS, 16 B per lane; LDS dest = wave-uniform base + lane*16
__device__ __forceinline__ void load16_lds(const void* g, void* l) {
    __builtin_amdgcn_global_load_lds(
        (const __attribute__((address_space(1))) uint32_t*)g,
        (__attribute__((address_space(3))) uint32_t*)l, 16, 0, 0);
}

// ======================= fp32 -> fp16 bulk convert =======================
__global__ __launch_bounds__(256) void convert_fp16(
    const float* __restrict__ X, _Float16* __restrict__ Xh, long n)
{
    long i = ((long)blockIdx.x * 256 + threadIdx.x) * 4;
    if (i < n) {
        floatx4 v = *(const floatx4*)(X + i);
        half4v h = { (_Float16)v[0], (_Float16)v[1], (_Float16)v[2], (_Float16)v[3] };
        *(half4v*)(Xh + i) = h;
    }
}

// ======================= W[K][N3] fp32 -> Wt[N3][K] fp16 =======================
__global__ __launch_bounds__(256) void transpose_w(
    const float* __restrict__ W, _Float16* __restrict__ Wt, int K)
{
    __shared__ float t[32][33];
    int k0 = blockIdx.x * 32, n0 = blockIdx.y * 32;
    int x  = threadIdx.x & 31;
    int y4 = (threadIdx.x >> 5) * 4;
    #pragma unroll
    for (int i = 0; i < 4; ++i)
        t[y4 + i][x] = W[(size_t)(k0 + y4 + i) * N3 + n0 + x];
    __syncthreads();
    #pragma unroll
    for (int i = 0; i < 4; ++i)
        Wt[(size_t)(n0 + y4 + i) * K + k0 + x] = (_Float16)t[x][y4 + i];
}

// ======================= GEMM + bias + act =======================
// ZFO = act(A[M,K] @ Wt[N3,K]^T + bias), fp32 out. A, Wt fp16.
// Tile 128x128, BK=32, 4 waves (2x2), 4x4 mfma_f32_16x16x32_f16/wave.
// LDS: unpadded [128][32] halfs, k-chunk XOR-swizzled: col = kb ^ ((row>>1)&3)
// -> ds_read_b128 phases hit all 32 banks 2x (free); staging via global_load_lds.
__global__ __launch_bounds__(256) void qrnn_gemm_bias_act(
    const _Float16* __restrict__ A,
    const _Float16* __restrict__ Wt,
    const float* __restrict__ bias,
    float* __restrict__ ZFO,
    int K)
{
    __shared__ _Float16 lds_a[128 * 32];
    __shared__ _Float16 lds_b[128 * 32];

    const int tid  = threadIdx.x;
    const int lane = tid & 63;
    const int w    = tid >> 6;
    const int wm   = w >> 1;
    const int wn   = w & 1;
    const int m0   = blockIdx.x * 128;
    const int n0   = blockIdx.y * 128;
    const int m16  = lane & 15;
    const int kb   = lane >> 4;
    const int swz  = (m16 >> 1) & 3;      // row-bit swizzle for fragment reads

    // staging: 512 slots of 16B per tile; wave w covers slots [w*128, w*128+128)
    // slot s -> row = s>>2, kb_g = (s&3) ^ ((row>>1)&3)
    const int s0   = w * 128 + lane;
    const int s1   = s0 + 64;
    const int row0 = s0 >> 2, kbg0 = (s0 & 3) ^ ((row0 >> 1) & 3);
    const int row1 = s1 >> 2, kbg1 = (s1 & 3) ^ ((row1 >> 1) & 3);
    _Float16* la0 = lds_a + (size_t)(w * 128) * 8;   // wave-uniform bases
    _Float16* la1 = la0 + 64 * 8;
    _Float16* lb0 = lds_b + (size_t)(w * 128) * 8;
    _Float16* lb1 = lb0 + 64 * 8;
    const _Float16* Ar0 = A  + (size_t)(m0 + row0) * K + kbg0 * 8;
    const _Float16* Ar1 = A  + (size_t)(m0 + row1) * K + kbg1 * 8;
    const _Float16* Br0 = Wt + (size_t)(n0 + row0) * K + kbg0 * 8;
    const _Float16* Br1 = Wt + (size_t)(n0 + row1) * K + kbg1 * 8;

    floatx4 acc[4][4] = {};

    for (int k0 = 0; k0 < K; k0 += 32) {
        load16_lds(Ar0 + k0, la0);
        load16_lds(Ar1 + k0, la1);
        load16_lds(Br0 + k0, lb0);
        load16_lds(Br1 + k0, lb1);
        __syncthreads();   // drains vmcnt (global_load_lds) before LDS reads

        half8 af[4], bf[4];
        #pragma unroll
        for (int i = 0; i < 4; ++i) {
            int r = wm * 64 + i * 16 + m16;
            af[i] = *(const half8*)&lds_a[r * 32 + (kb ^ swz) * 8];
        }
        #pragma unroll
        for (int j = 0; j < 4; ++j) {
            int r = wn * 64 + j * 16 + m16;
            bf[j] = *(const half8*)&lds_b[r * 32 + (kb ^ swz) * 8];
        }
        #pragma unroll
        for (int i = 0; i < 4; ++i)
            #pragma unroll
            for (int j = 0; j < 4; ++j)
                acc[i][j] = __builtin_amdgcn_mfma_f32_16x16x32_f16(
                                af[i], bf[j], acc[i][j], 0, 0, 0);
        __syncthreads();   // LDS consumed; safe to overwrite next iter
    }

    // epilogue: D row=(lane>>4)*4+r, col=lane&15
    const int rbase = (lane >> 4) * 4;
    const int cbase = lane & 15;
    #pragma unroll
    for (int i = 0; i < 4; ++i) {
        #pragma unroll
        for (int j = 0; j < 4; ++j) {
            int n = n0 + wn * 64 + j * 16 + cbase;
            float bv = bias[n];
            #pragma unroll
            for (int r = 0; r < 4; ++r) {
                int m = m0 + wm * 64 + i * 16 + rbase + r;
                float v = acc[i][j][r] + bv;
                if (n < HID) v = tanhf(v);
                else         v = 1.0f / (1.0f + __expf(-v));
                ZFO[(size_t)m * N3 + n] = v;
            }
        }
    }
}

// ======================= chunked parallel scan =======================
// c_s = f*c + (1-f)*z; chunk of LCH reduces to c_out = F*c_in + C.
// Thread handles 2 adjacent h (float2). Summary layout: [b][chunk][hh].

__global__ __launch_bounds__(256) void qrnn_scan_sum(
    const float* __restrict__ ZFO,
    floatx2* __restrict__ Fs, floatx2* __restrict__ Cs,
    int reverse)
{
    int t  = blockIdx.x * 256 + threadIdx.x;
    int hh = t & 255;
    int bj = t >> 8;
    int j  = bj & (NC - 1);
    int b  = bj >> NCLOG;
    int h2 = hh * 2;
    const float* base = ZFO + (size_t)b * SQ * N3 + h2;
    float F0 = 1.f, F1 = 1.f, c0 = 0.f, c1 = 0.f;
    int s0 = j * LCH;
    #pragma unroll 4
    for (int i = 0; i < LCH; ++i) {
        int s = reverse ? (s0 + LCH - 1 - i) : (s0 + i);
        const float* p = base + (size_t)s * N3;
        floatx2 z = *(const floatx2*)p;
        floatx2 f = *(const floatx2*)(p + HID);
        F0 *= f[0]; F1 *= f[1];
        c0 = f[0] * c0 + (1.f - f[0]) * z[0];
        c1 = f[1] * c1 + (1.f - f[1]) * z[1];
    }
    Fs[(size_t)bj * 256 + hh] = floatx2{F0, F1};
    Cs[(size_t)bj * 256 + hh] = floatx2{c0, c1};
}

__global__ __launch_bounds__(256) void qrnn_scan_mid(
    const floatx2* __restrict__ Fs, const floatx2* __restrict__ Cs,
    floatx2* __restrict__ cin, int reverse)
{
    int t  = blockIdx.x * 256 + threadIdx.x;
    int hh = t & 255;
    int b  = t >> 8;
    float c0 = 0.f, c1 = 0.f;
    for (int i = 0; i < NC; ++i) {
        int j = reverse ? (NC - 1 - i) : i;
        size_t idx = ((size_t)b * NC + j) * 256 + hh;
        cin[idx] = floatx2{c0, c1};
        floatx2 F = Fs[idx], C = Cs[idx];
        c0 = F[0] * c0 + C[0];
        c1 = F[1] * c1 + C[1];
    }
}

template <typename OT>
__global__ __launch_bounds__(256) void qrnn_scan_out(
    const float* __restrict__ ZFO,
    const floatx2* __restrict__ cin,
    OT* __restrict__ out,            // chunk-batch base, row stride N2
    int reverse, int col_ofs)
{
    int t  = blockIdx.x * 256 + threadIdx.x;
    int hh = t & 255;
    int bj = t >> 8;
    int j  = bj & (NC - 1);
    int b  = bj >> NCLOG;
    int h2 = hh * 2;
    const float* base = ZFO + (size_t)b * SQ * N3 + h2;
    floatx2 c = cin[(size_t)bj * 256 + hh];
    float c0 = c[0], c1 = c[1];
    int s0 = j * LCH;
    #pragma unroll 4
    for (int i = 0; i < LCH; ++i) {
        int s = reverse ? (s0 + LCH - 1 - i) : (s0 + i);
        const float* p = base + (size_t)s * N3;
        floatx2 z = *(const floatx2*)p;
        floatx2 f = *(const floatx2*)(p + HID);
        floatx2 o = *(const floatx2*)(p + 2 * HID);
        c0 = f[0] * c0 + (1.f - f[0]) * z[0];
        c1 = f[1] * c1 + (1.f - f[1]) * z[1];
        OT* q = out + (size_t)(b * SQ + s) * N2 + col_ofs + h2;
        if constexpr (std::is_same<OT, float>::value) {
            *(floatx2*)q = floatx2{o[0] * c0, o[1] * c1};
        } else {
            *(half2v*)q = half2v{(_Float16)(o[0] * c0), (_Float16)(o[1] * c1)};
        }
    }
}

// ======================= launcher =======================
extern "C" void kernel_launch(void* const* d_in, const int* in_sizes, int n_in,
                              void* d_out, int out_size, void* d_ws, size_t ws_size,
                              hipStream_t stream)
{
    const float* X = (const float*)d_in[0];
    const float* Wd[2][2] = {
        { (const float*)d_in[2], (const float*)d_in[4] },
        { (const float*)d_in[6], (const float*)d_in[8] } };
    const float* bd[2][2] = {
        { (const float*)d_in[3], (const float*)d_in[5] },
        { (const float*)d_in[7], (const float*)d_in[9] } };
    float* OUT = (float*)d_out;

    // ws: Y1 fp16 (64MB) | Xh fp16 (32MB) | Wt fp16 (3MB) | Fs|Cs|cin (2MB ea) | ZFO chunk
    char* p = (char*)d_ws;
    _Float16* Y1 = (_Float16*)p;  p += (size_t)NB * SQ * N2 * sizeof(_Float16);
    _Float16* Xh = (_Float16*)p;  p += (size_t)NB * SQ * 512 * sizeof(_Float16);
    _Float16* Wt = (_Float16*)p;  p += (size_t)N3 * 1024 * sizeof(_Float16);
    size_t sum_elems = (size_t)NB * NC * 256;
    floatx2* Fs  = (floatx2*)p;   p += sum_elems * sizeof(floatx2);
    floatx2* Cs  = (floatx2*)p;   p += sum_elems * sizeof(floatx2);
    floatx2* cin = (floatx2*)p;   p += sum_elems * sizeof(floatx2);
    float* ZFO = (float*)p;
    size_t used  = (size_t)(p - (char*)d_ws);
    size_t per_b = (size_t)SQ * N3 * sizeof(float);
    size_t avail = (ws_size > used) ? (ws_size - used) : per_b;
    int cbmax = (int)(avail / per_b);
    if (cbmax > NB) cbmax = NB;
    if (cbmax < 1)  cbmax = 1;

    // X -> fp16 once (reused by both layer-1 dirs)
    {
        long n = (long)NB * SQ * 512;
        convert_fp16<<<(int)(n / 4 / 256), 256, 0, stream>>>(X, Xh, n);
    }

    for (int layer = 0; layer < 2; ++layer) {
        int K = (layer == 0) ? 512 : 1024;
        const _Float16* Ah = (layer == 0) ? Xh : Y1;
        for (int dir = 0; dir < 2; ++dir) {
            // W[K][N3] fp32 -> Wt[N3][K] fp16
            transpose_w<<<dim3(K / 32, N3 / 32), 256, 0, stream>>>(
                Wd[layer][dir], Wt, K);
            int colofs = (dir == 0) ? 0 : HID;
            for (int c0 = 0; c0 < NB; c0 += cbmax) {
                int cb = (cbmax < NB - c0) ? cbmax : (NB - c0);
                int M = cb * SQ;
                dim3 grid(M / 128, N3 / 128);
                qrnn_gemm_bias_act<<<grid, 256, 0, stream>>>(
                    Ah + (size_t)c0 * SQ * K, Wt, bd[layer][dir], ZFO, K);
                qrnn_scan_sum<<<cb * NC, 256, 0, stream>>>(ZFO, Fs, Cs, dir);
                qrnn_scan_mid<<<cb, 256, 0, stream>>>(Fs, Cs, cin, dir);
                if (layer == 0) {
                    qrnn_scan_out<_Float16><<<cb * NC, 256, 0, stream>>>(
                        ZFO, cin, Y1 + (size_t)c0 * SQ * N2, dir, colofs);
                } else {
                    qrnn_scan_out<float><<<cb * NC, 256, 0, stream>>>(
                        ZFO, cin, OUT + (size_t)c0 * SQ * N2, dir, colofs);
                }
            }
        }
    }
}